// Round 4
// baseline (261.779 us; speedup 1.0000x reference)
//
#include <hip/hip_runtime.h>

typedef __bf16 bf16_t;
typedef __bf16 bf16x8 __attribute__((ext_vector_type(8)));
typedef __bf16 bf16x4 __attribute__((ext_vector_type(4)));
typedef float f32x4 __attribute__((ext_vector_type(4)));

#define B_  2
#define N_  2048
#define D_  1024
#define H_  16
#define DH_ 64

#define GLL16(g, l) __builtin_amdgcn_global_load_lds( \
    (const __attribute__((address_space(1))) void*)(g), \
    (__attribute__((address_space(3))) void*)(l), 16, 0, 0)

// ---------------- trig table: trig[n][j] = (cos(n*f_j), sin(n*f_j)), accurate libm ----------------
__global__ __launch_bounds__(256) void k_trig(const float* __restrict__ freqs,
    float2* __restrict__ trig) {
  int i = blockIdx.x * 256 + threadIdx.x;     // 0..65535
  int n = i >> 5, j = i & 31;
  float f = (float)n * freqs[j];
  trig[i] = make_float2(cosf(f), sinf(f));    // accurate: args up to ~2047 rad
}

// ---------------- RMSNorm: xn = x * (32/||x||) * gamma, bf16 out ----------------
__global__ __launch_bounds__(256) void k_rmsnorm(const float* __restrict__ x,
    const float* __restrict__ gamma, bf16_t* __restrict__ xn) {
  int row = blockIdx.x;
  const float4* xr = (const float4*)(x + (size_t)row * D_);
  int tid = threadIdx.x;
  float4 v = xr[tid];
  float ss = v.x*v.x + v.y*v.y + v.z*v.z + v.w*v.w;
  #pragma unroll
  for (int off = 32; off > 0; off >>= 1) ss += __shfl_down(ss, off);
  __shared__ float red[4];
  if ((tid & 63) == 0) red[tid >> 6] = ss;
  __syncthreads();
  float scale = 32.0f * rsqrtf(red[0] + red[1] + red[2] + red[3]);
  float4 g = ((const float4*)gamma)[tid];
  bf16x4 o;
  o[0] = (bf16_t)(v.x * scale * g.x);
  o[1] = (bf16_t)(v.y * scale * g.y);
  o[2] = (bf16_t)(v.z * scale * g.z);
  o[3] = (bf16_t)(v.w * scale * g.w);
  *(bf16x4*)(xn + (size_t)row * D_ + tid * 4) = o;
}

// ---------------- transpose fp32 [R][C] -> bf16 [C][R] ----------------
__global__ __launch_bounds__(256) void k_transpose_cvt(const float* __restrict__ W,
    bf16_t* __restrict__ Wt, int R, int C) {
  __shared__ float tile[32][33];
  int c0 = blockIdx.x * 32, r0 = blockIdx.y * 32;
  int tx = threadIdx.x & 31, ty = threadIdx.x >> 5;
  #pragma unroll
  for (int i = 0; i < 4; ++i) {
    int r = ty + i * 8;
    tile[r][tx] = W[(size_t)(r0 + r) * C + c0 + tx];
  }
  __syncthreads();
  #pragma unroll
  for (int i = 0; i < 4; ++i) {
    int rr = ty + i * 8;
    Wt[(size_t)(c0 + rr) * R + r0 + tx] = (bf16_t)tile[tx][rr];
  }
}

// ---------------- QKV GEMM + fused RoPE/scatter epilogue ----------------
__global__ __launch_bounds__(256) void k_gemm_qkv(const bf16_t* __restrict__ A,
    const bf16_t* __restrict__ Bt, const float2* __restrict__ trig,
    bf16_t* __restrict__ Qb, bf16_t* __restrict__ Kb, bf16_t* __restrict__ Vb) {
  constexpr int BK = 32, K = 1024;
  __shared__ __align__(16) bf16_t As[128 * BK];
  __shared__ __align__(16) bf16_t Bs[128 * BK];
  int tid = threadIdx.x, wave = tid >> 6, lane = tid & 63;
  int l16 = lane & 15, quad = lane >> 4;
  int bm = blockIdx.x * 128, bn = blockIdx.y * 128;
  int wm = (wave >> 1) * 64, wn = (wave & 1) * 64;
  int srow = wave * 32 + (lane >> 2);
  int scol = (lane & 3) * 8;
  const bf16_t* gA0 = &A [(size_t)(bm + srow)      * K + scol];
  const bf16_t* gA1 = &A [(size_t)(bm + srow + 16) * K + scol];
  const bf16_t* gB0 = &Bt[(size_t)(bn + srow)      * K + scol];
  const bf16_t* gB1 = &Bt[(size_t)(bn + srow + 16) * K + scol];
  bf16_t* lA0 = &As[(wave * 32)      * BK];
  bf16_t* lA1 = &As[(wave * 32 + 16) * BK];
  bf16_t* lB0 = &Bs[(wave * 32)      * BK];
  bf16_t* lB1 = &Bs[(wave * 32 + 16) * BK];
  f32x4 acc[4][4] = {};
  for (int k0 = 0; k0 < K; k0 += BK) {
    GLL16(gA0 + k0, lA0);
    GLL16(gA1 + k0, lA1);
    GLL16(gB0 + k0, lB0);
    GLL16(gB1 + k0, lB1);
    __syncthreads();
    bf16x8 af[4], bfr[4];
    #pragma unroll
    for (int t = 0; t < 4; ++t) {
      af[t]  = *(const bf16x8*)&As[(wm + t * 16 + l16) * BK + quad * 8];
      bfr[t] = *(const bf16x8*)&Bs[(wn + t * 16 + l16) * BK + quad * 8];
    }
    #pragma unroll
    for (int mt = 0; mt < 4; ++mt)
      #pragma unroll
      for (int nt = 0; nt < 4; ++nt)
        acc[mt][nt] = __builtin_amdgcn_mfma_f32_16x16x32_bf16(af[mt], bfr[nt], acc[mt][nt], 0, 0, 0);
    __syncthreads();
  }
  int type = bn >> 10;                          // 0=q 1=k 2=v (block-uniform)
  int h = (((bn & 1023) + wn) >> 6);            // wave-uniform head
  if (type < 2) {
    bf16_t* dst = (type == 0) ? Qb : Kb;
    float qsc = (type == 0) ? 0.125f : 1.0f;
    #pragma unroll
    for (int nt = 0; nt < 4; ++nt) {
      int d = nt * 16 + l16;                    // 0..63 within head
      int j = d >> 1;
      bool odd = (d & 1);
      #pragma unroll
      for (int mt = 0; mt < 4; ++mt)
        #pragma unroll
        for (int r = 0; r < 4; ++r) {
          int row = bm + wm + mt * 16 + quad * 4 + r;
          int b = row >> 11, n = row & 2047;
          float v = acc[mt][nt][r];
          float vp = __shfl_xor(v, 1);
          float2 cs = trig[n * 32 + j];
          float o = odd ? (v * cs.x + vp * cs.y) : (v * cs.x - vp * cs.y);
          dst[((size_t)(b * H_ + h) * N_ + n) * DH_ + d] = (bf16_t)(o * qsc);
        }
    }
  } else {
    #pragma unroll
    for (int mt = 0; mt < 4; ++mt) {
      int row0 = bm + wm + mt * 16 + quad * 4;
      int b = row0 >> 11, n0 = row0 & 2047;
      #pragma unroll
      for (int nt = 0; nt < 4; ++nt) {
        int d = nt * 16 + l16;
        bf16x4 pk;
        #pragma unroll
        for (int r = 0; r < 4; ++r) pk[r] = (bf16_t)acc[mt][nt][r];
        *(bf16x4*)&Vb[((size_t)(b * H_ + h) * DH_ + d) * N_ + n0] = pk;
      }
    }
  }
}

// ---------------- out-proj GEMM: 64x128 tile, fp32 out ----------------
__global__ __launch_bounds__(256) void k_gemm_out(const bf16_t* __restrict__ A,
    const bf16_t* __restrict__ Bt, float* __restrict__ C, int M, int N, int K) {
  constexpr int BK = 32;
  __shared__ __align__(16) bf16_t As[64 * BK];
  __shared__ __align__(16) bf16_t Bs[128 * BK];
  int tid = threadIdx.x, wave = tid >> 6, lane = tid & 63;
  int l16 = lane & 15, quad = lane >> 4;
  int bm = blockIdx.x * 64, bn = blockIdx.y * 128;
  int wm = (wave >> 1) * 32, wn = (wave & 1) * 64;
  int srowA = wave * 16 + (lane >> 2);
  int srowB = wave * 32 + (lane >> 2);
  int scol = (lane & 3) * 8;
  const bf16_t* gA0 = &A [(size_t)(bm + srowA)      * K + scol];
  const bf16_t* gB0 = &Bt[(size_t)(bn + srowB)      * K + scol];
  const bf16_t* gB1 = &Bt[(size_t)(bn + srowB + 16) * K + scol];
  bf16_t* lA0 = &As[(wave * 16)      * BK];
  bf16_t* lB0 = &Bs[(wave * 32)      * BK];
  bf16_t* lB1 = &Bs[(wave * 32 + 16) * BK];
  f32x4 acc[2][4] = {};
  for (int k0 = 0; k0 < K; k0 += BK) {
    GLL16(gA0 + k0, lA0);
    GLL16(gB0 + k0, lB0);
    GLL16(gB1 + k0, lB1);
    __syncthreads();
    bf16x8 af[2], bfr[4];
    #pragma unroll
    for (int t = 0; t < 2; ++t)
      af[t] = *(const bf16x8*)&As[(wm + t * 16 + l16) * BK + quad * 8];
    #pragma unroll
    for (int t = 0; t < 4; ++t)
      bfr[t] = *(const bf16x8*)&Bs[(wn + t * 16 + l16) * BK + quad * 8];
    #pragma unroll
    for (int mt = 0; mt < 2; ++mt)
      #pragma unroll
      for (int nt = 0; nt < 4; ++nt)
        acc[mt][nt] = __builtin_amdgcn_mfma_f32_16x16x32_bf16(af[mt], bfr[nt], acc[mt][nt], 0, 0, 0);
    __syncthreads();
  }
  #pragma unroll
  for (int mt = 0; mt < 2; ++mt)
    #pragma unroll
    for (int nt = 0; nt < 4; ++nt)
      #pragma unroll
      for (int r = 0; r < 4; ++r) {
        int row = bm + wm + mt * 16 + quad * 4 + r;
        int col = bn + wn + nt * 16 + l16;
        C[(size_t)row * N + col] = acc[mt][nt][r];
      }
}

// ---------------- gates: gsig[row][h] = sigmoid(xn . wg[:,h] + bg[h]) ----------------
__global__ __launch_bounds__(256) void k_gates(const bf16_t* __restrict__ xn,
    const float* __restrict__ wg, const float* __restrict__ bg,
    float* __restrict__ gsig) {
  int row = blockIdx.x;
  int tid = threadIdx.x;
  int h = tid & 15, seg = tid >> 4;
  const bf16_t* xr = xn + (size_t)row * D_;
  float part = 0.f;
  #pragma unroll 8
  for (int j = 0; j < 64; ++j) {
    int i = seg * 64 + j;
    part += (float)xr[i] * wg[i * 16 + h];
  }
  __shared__ float red[16][17];
  red[seg][h] = part;
  __syncthreads();
  if (tid < 16) {
    float s = bg[tid];
    #pragma unroll
    for (int sg = 0; sg < 16; ++sg) s += red[sg][tid];
    gsig[(size_t)row * 16 + tid] = 1.0f / (1.0f + __expf(-s));
  }
}

// ---------------- flash attention, key-split 2-way, fp32 additive partials ----------------
__global__ __launch_bounds__(256) void k_flash(const bf16_t* __restrict__ Qb,
    const bf16_t* __restrict__ Kb, const bf16_t* __restrict__ Vb,
    float* __restrict__ Op0, float* __restrict__ Op1, float* __restrict__ Lpart) {
  __shared__ __align__(16) bf16_t Ks[64 * 72];
  __shared__ __align__(16) bf16_t Vt[64 * 72];
  __shared__ __align__(16) bf16_t Ps[4][32 * 72];
  int bh = blockIdx.y, b = bh >> 4, h = bh & 15;
  int split = blockIdx.z;
  int tid = threadIdx.x, wave = tid >> 6, lane = tid & 63;
  int l16 = lane & 15, quad = lane >> 4;
  int qw = blockIdx.x * 128 + wave * 32;
  const bf16_t* Qh = Qb + (size_t)bh * N_ * DH_;
  const bf16_t* Kh = Kb + (size_t)bh * N_ * DH_;
  const bf16_t* Vh = Vb + (size_t)bh * DH_ * N_;
  bf16_t* Pw = Ps[wave];
  bf16x8 qf[2][2];
  #pragma unroll
  for (int qt = 0; qt < 2; ++qt)
    #pragma unroll
    for (int hf = 0; hf < 2; ++hf)
      qf[qt][hf] = *(const bf16x8*)&Qh[(size_t)(qw + qt * 16 + l16) * DH_ + hf * 32 + quad * 8];
  f32x4 accO[2][4] = {};
  float lsum[2] = {0.f, 0.f};
  int sk = tid >> 3;
  int sc = (tid & 7) * 8;
  int kbeg = split * (N_ / 2), kend = kbeg + N_ / 2;
  for (int k0 = kbeg; k0 < kend; k0 += 64) {
    *(bf16x8*)&Ks[sk * 72 + sc]        = *(const bf16x8*)&Kh[(size_t)(k0 + sk) * DH_ + sc];
    *(bf16x8*)&Ks[(sk + 32) * 72 + sc] = *(const bf16x8*)&Kh[(size_t)(k0 + sk + 32) * DH_ + sc];
    *(bf16x8*)&Vt[sk * 72 + sc]        = *(const bf16x8*)&Vh[(size_t)sk * N_ + k0 + sc];
    *(bf16x8*)&Vt[(sk + 32) * 72 + sc] = *(const bf16x8*)&Vh[(size_t)(sk + 32) * N_ + k0 + sc];
    __syncthreads();
    f32x4 st[4][2];
    #pragma unroll
    for (int kt = 0; kt < 4; ++kt) {
      bf16x8 kf0 = *(const bf16x8*)&Ks[(kt * 16 + l16) * 72 + quad * 8];
      bf16x8 kf1 = *(const bf16x8*)&Ks[(kt * 16 + l16) * 72 + 32 + quad * 8];
      #pragma unroll
      for (int qt = 0; qt < 2; ++qt) {
        f32x4 z = {};
        z = __builtin_amdgcn_mfma_f32_16x16x32_bf16(kf0, qf[qt][0], z, 0, 0, 0);
        z = __builtin_amdgcn_mfma_f32_16x16x32_bf16(kf1, qf[qt][1], z, 0, 0, 0);
        st[kt][qt] = z;
      }
    }
    #pragma unroll
    for (int qt = 0; qt < 2; ++qt)
      #pragma unroll
      for (int kt = 0; kt < 4; ++kt) {
        bf16x4 pk;
        #pragma unroll
        for (int r = 0; r < 4; ++r) {
          float p = __expf(st[kt][qt][r] - 8.0f);
          lsum[qt] += p;
          pk[r] = (bf16_t)p;
        }
        *(bf16x4*)&Pw[(qt * 16 + l16) * 72 + kt * 16 + quad * 4] = pk;
      }
    bf16x8 pf[2][2];
    #pragma unroll
    for (int qt = 0; qt < 2; ++qt)
      #pragma unroll
      for (int hf = 0; hf < 2; ++hf)
        pf[qt][hf] = *(const bf16x8*)&Pw[(qt * 16 + l16) * 72 + hf * 32 + quad * 8];
    #pragma unroll
    for (int dt = 0; dt < 4; ++dt)
      #pragma unroll
      for (int hf = 0; hf < 2; ++hf) {
        bf16x8 vf = *(const bf16x8*)&Vt[(dt * 16 + l16) * 72 + hf * 32 + quad * 8];
        #pragma unroll
        for (int qt = 0; qt < 2; ++qt)
          accO[qt][dt] = __builtin_amdgcn_mfma_f32_16x16x32_bf16(pf[qt][hf], vf, accO[qt][dt], 0, 0, 0);
      }
    __syncthreads();
  }
  float lfull[2];
  #pragma unroll
  for (int qt = 0; qt < 2; ++qt) {
    float s = lsum[qt];
    s += __shfl_xor(s, 16);
    s += __shfl_xor(s, 32);
    lfull[qt] = s;
  }
  float* Op = (split == 0) ? Op0 : Op1;
  #pragma unroll
  for (int qt = 0; qt < 2; ++qt) {
    if (quad == 0) {
      int q = qw + qt * 16 + l16;
      Lpart[(size_t)split * 65536 + ((size_t)b * N_ + q) * H_ + h] = lfull[qt];
    }
    #pragma unroll
    for (int r = 0; r < 4; ++r) {
      int q = qw + qt * 16 + quad * 4 + r;
      size_t base = ((size_t)b * N_ + q) * 1024 + h * DH_;
      #pragma unroll
      for (int dt = 0; dt < 4; ++dt)
        Op[base + dt * 16 + l16] = accO[qt][dt][r];
    }
  }
}

// ---------------- merge: attn = (O0+O1) * g / (l0+l1), bf16 ----------------
__global__ __launch_bounds__(256) void k_merge(const float* __restrict__ Op0,
    const float* __restrict__ Op1, const float* __restrict__ Lpart,
    const float* __restrict__ gsig, bf16_t* __restrict__ attn) {
  int row = blockIdx.x, tid = threadIdx.x;
  int col = tid * 4, h = col >> 6;
  float l = Lpart[(size_t)row * H_ + h] + Lpart[65536 + (size_t)row * H_ + h];
  float g = gsig[(size_t)row * H_ + h];
  float sc = g / l;
  float4 a0 = *(const float4*)&Op0[(size_t)row * 1024 + col];
  float4 a1 = *(const float4*)&Op1[(size_t)row * 1024 + col];
  bf16x4 o;
  o[0] = (bf16_t)((a0.x + a1.x) * sc);
  o[1] = (bf16_t)((a0.y + a1.y) * sc);
  o[2] = (bf16_t)((a0.z + a1.z) * sc);
  o[3] = (bf16_t)((a0.w + a1.w) * sc);
  *(bf16x4*)&attn[(size_t)row * 1024 + col] = o;
}

extern "C" void kernel_launch(void* const* d_in, const int* in_sizes, int n_in,
                              void* d_out, int out_size, void* d_ws, size_t ws_size,
                              hipStream_t stream) {
  (void)in_sizes; (void)n_in; (void)out_size; (void)ws_size;
  const float* x      = (const float*)d_in[0];
  const float* gamma  = (const float*)d_in[1];
  const float* w_qkv  = (const float*)d_in[2];
  const float* w_gate = (const float*)d_in[3];
  const float* b_gate = (const float*)d_in[4];
  const float* w_out  = (const float*)d_in[5];
  const float* freqs  = (const float*)d_in[6];
  float* out = (float*)d_out;
  char* ws = (char*)d_ws;
  // layout (MB). Opart0 overlays xn+wqkvT (both dead before flash). Peak ~68.5 MB.
  bf16_t* xn    = (bf16_t*)(ws);                          // 8 MB  (dead after k_gates)
  bf16_t* wqkvT = (bf16_t*)(ws + ((size_t)8  << 20));     // 6 MB  (dead after k_gemm_qkv)
  float*  Opart0= (float*) (ws);                          // 16 MB (flash, overlays the two above)
  bf16_t* Qb    = (bf16_t*)(ws + ((size_t)16 << 20));     // 8 MB [bh][n][64]
  bf16_t* Kb    = (bf16_t*)(ws + ((size_t)24 << 20));     // 8 MB [bh][n][64]
  bf16_t* Vb    = (bf16_t*)(ws + ((size_t)32 << 20));     // 8 MB [bh][64][n]
  float*  gsig  = (float*) (ws + ((size_t)40 << 20));     // 256 KB
  bf16_t* attn  = (bf16_t*)(ws + ((size_t)41 << 20));     // 8 MB
  float*  Opart1= (float*) (ws + ((size_t)49 << 20));     // 16 MB
  float*  Lpart = (float*) (ws + ((size_t)65 << 20));     // 512 KB
  bf16_t* woutT = (bf16_t*)(ws + ((size_t)66 << 20));     // 2 MB
  float2* trig  = (float2*)(ws + ((size_t)68 << 20));     // 512 KB

  k_trig<<<256, 256, 0, stream>>>(freqs, trig);
  k_transpose_cvt<<<dim3(3072 / 32, 1024 / 32), 256, 0, stream>>>(w_qkv, wqkvT, 1024, 3072);
  k_transpose_cvt<<<dim3(1024 / 32, 1024 / 32), 256, 0, stream>>>(w_out, woutT, 1024, 1024);
  k_rmsnorm<<<4096, 256, 0, stream>>>(x, gamma, xn);
  k_gemm_qkv<<<dim3(32, 24), 256, 0, stream>>>(xn, wqkvT, trig, Qb, Kb, Vb);
  k_gates<<<4096, 256, 0, stream>>>(xn, w_gate, b_gate, gsig);
  k_flash<<<dim3(16, 32, 2), 256, 0, stream>>>(Qb, Kb, Vb, Opart0, Opart1, Lpart);
  k_merge<<<4096, 256, 0, stream>>>(Opart0, Opart1, Lpart, gsig, attn);
  k_gemm_out<<<dim3(64, 8), 256, 0, stream>>>(attn, woutT, out, 4096, 1024, 1024);
}